// Round 5
// baseline (574.213 us; speedup 1.0000x reference)
//
#include <hip/hip_runtime.h>

// Problem constants (fixed by the reference)
#define D_   8
#define Q_   1024
#define DB_  32768
#define F_   64
#define NB_  128      // num_buckets = num_neighbors
#define BS_  256      // bucket_size = DB/NB
#define NT_  (Q_*D_*NB_)   // 1,048,576 (q,d,j) triples
#define SPLIT_ 4      // split of the b-range across blocks
#define MARGIN_ 0.04f // top-2 gap below which we escalate to fp64 exact path
                      // (fp16 single-pass score err sigma ~3.4e-3; 0.04 ~ 7-sigma
                      //  of the top-2 error difference -> miss prob ~1e-9/triple;
                      //  flags ~1.5% of 1M triples -> k_fix absorbs them)

typedef __attribute__((ext_vector_type(16))) float     f32x16;
typedef __attribute__((ext_vector_type(8)))  short     short8;
typedef __attribute__((ext_vector_type(8)))  _Float16  half8;
typedef __attribute__((ext_vector_type(4)))  _Float16  half4f;

static __device__ __forceinline__ f32x16 mfma16(short8 a, short8 b, f32x16 c) {
    return __builtin_amdgcn_mfma_f32_32x32x16_f16(
        __builtin_bit_cast(half8, a), __builtin_bit_cast(half8, b), c, 0, 0, 0);
}

// ---------------------------------------------------------------------------
// fp32 -> fp16 (RNE) key conversion. 16B stores.
// ---------------------------------------------------------------------------
__global__ void k_conv16(const float* __restrict__ src, _Float16* __restrict__ dst,
                         int n8)
{
    for (int i = blockIdx.x * 256 + threadIdx.x; i < n8; i += gridDim.x * 256) {
        float4 a = ((const float4*)src)[2 * i];
        float4 b = ((const float4*)src)[2 * i + 1];
        half8 h = { (_Float16)a.x, (_Float16)a.y, (_Float16)a.z, (_Float16)a.w,
                    (_Float16)b.x, (_Float16)b.y, (_Float16)b.z, (_Float16)b.w };
        ((half8*)dst)[i] = h;
    }
}

// Query conversion with (Q,D,F) -> (D,Q,F) transpose, fp32 -> fp16.
__global__ void k_convq16(const float* __restrict__ q, _Float16* __restrict__ dst)
{
    int i = blockIdx.x * 256 + threadIdx.x;   // exactly Q_*D_*F_/4 threads
    int c = i & 15, d = (i >> 4) & 7, qq = i >> 7;
    float4 v = *(const float4*)(q + ((size_t)qq * D_ + d) * F_ + c * 4);
    half4f h = { (_Float16)v.x, (_Float16)v.y, (_Float16)v.z, (_Float16)v.w };
    *(half4f*)(dst + ((size_t)d * Q_ + qq) * F_ + c * 4) = h;
}

// ---------------------------------------------------------------------------
// K1: fp16 single-pass MFMA scan. Block = 64q x 128j (512 thr, 8 waves =
// 2 qg x 4 jg), each wave one 32x32 tile per step. 2 b-steps per barrier
// phase (32 phases), double-buffered 72KB LDS (rows padded +8 fp16), loads
// for phase p+1 issued before phase-p compute. 2 blocks/CU.
// L2 budget: slab per (d,half) = 64 steps x 128 j x 64 F x 2B = 1MB; swizzle
// gives 4 slabs = 4MB per XCD (= L2), each shared by 16 co-resident blocks.
// ---------------------------------------------------------------------------
__global__ __launch_bounds__(512, 4) void k_scan_mfma(
    const _Float16* __restrict__ kdb, const _Float16* __restrict__ qdb,
    float* __restrict__ m1p, float* __restrict__ m2p, int* __restrict__ b1p)
{
    __shared__ _Float16 kbuf[2][2][128][72];   // [buf][step][row][col] = 72 KB
    const int tid = threadIdx.x;
    // XCD swizzle: w = [half(2b) | d(3b) | qi(4b)], 64 contiguous w per XCD
    // -> per XCD: 16 qi x 4 (d,half) slabs.
    const int w    = (blockIdx.x >> 3) | ((blockIdx.x & 7) << 6);
    const int qi   = w & 15;
    const int d    = (w >> 4) & 7;
    const int half = w >> 7;               // 0..SPLIT_-1
    const int q0 = qi * 64;
    const int wv = tid >> 6, lane = tid & 63;
    const int qg = wv >> 2, jg = wv & 3;
    const int lrow = lane & 31, kg = lane >> 5;

    // hoist Q fragments (A-operand): row = lane&31, 8 fp16 at f = ks*16+kg*8
    short8 qf[4];
    {
        const _Float16* qp = qdb + ((size_t)d * Q_ + q0 + qg * 32 + lrow) * F_ + kg * 8;
#pragma unroll
        for (int ks = 0; ks < 4; ++ks) qf[ks] = *(const short8*)(qp + ks * 16);
    }

    float m1[16], m2[16]; int b1[16];
#pragma unroll
    for (int r = 0; r < 16; ++r) { m1[r] = -3e38f; m2[r] = -3e38f; b1[r] = 0; }

    const int bstart = half * (BS_ / SPLIT_);          // 64 steps per block
    // staging map: thread t handles 4 x 16B chunks; r0 = t>>3, sub = t&7
    const int r0 = tid >> 3, sub = tid & 7;
    const _Float16* sp = kdb + (size_t)d * DB_ * F_ + (size_t)bstart * NB_ * F_
                       + (size_t)r0 * F_ + sub * 8;
    // phase stride = 2 steps * 128 rows * 64 F = 16384 fp16

    { // prologue: stage phase 0 into buf 0
        short8 g0 = *(const short8*)(sp);
        short8 g1 = *(const short8*)(sp + 4096);
        short8 g2 = *(const short8*)(sp + 8192);
        short8 g3 = *(const short8*)(sp + 12288);
        *(short8*)&kbuf[0][0][r0     ][sub * 8] = g0;
        *(short8*)&kbuf[0][0][r0 + 64][sub * 8] = g1;
        *(short8*)&kbuf[0][1][r0     ][sub * 8] = g2;
        *(short8*)&kbuf[0][1][r0 + 64][sub * 8] = g3;
    }

    const int jrow = jg * 32 + lrow;       // j index 0..127
    int cur = 0;
    for (int p = 0; p < 32; ++p) {
        __syncthreads();                   // buf[cur] ready; buf[cur^1] free
        short8 g0, g1, g2, g3;
        if (p < 31) {                      // issue next-phase loads early
            const _Float16* np = sp + (size_t)(p + 1) * 16384;
            g0 = *(const short8*)(np);
            g1 = *(const short8*)(np + 4096);
            g2 = *(const short8*)(np + 8192);
            g3 = *(const short8*)(np + 12288);
        }
#pragma unroll
        for (int s = 0; s < 2; ++s) {
            short8 kf[4];
#pragma unroll
            for (int ks = 0; ks < 4; ++ks)
                kf[ks] = *(const short8*)&kbuf[cur][s][jrow][ks * 16 + kg * 8];
            f32x16 c = {0,0,0,0,0,0,0,0,0,0,0,0,0,0,0,0};
            c = mfma16(qf[0], kf[0], c);
            c = mfma16(qf[1], kf[1], c);
            c = mfma16(qf[2], kf[2], c);
            c = mfma16(qf[3], kf[3], c);
            const int b = bstart + 2 * p + s;
            // branchless top-2: med3 = new 2nd-max in one instruction
#pragma unroll
            for (int r = 0; r < 16; ++r) {
                float v = c[r];
                b1[r] = (v > m1[r]) ? b : b1[r];
                m2[r] = __builtin_amdgcn_fmed3f(v, m1[r], m2[r]);
                m1[r] = fmaxf(m1[r], v);
            }
        }
        if (p < 31) {
            const int nb = cur ^ 1;
            *(short8*)&kbuf[nb][0][r0     ][sub * 8] = g0;
            *(short8*)&kbuf[nb][0][r0 + 64][sub * 8] = g1;
            *(short8*)&kbuf[nb][1][r0     ][sub * 8] = g2;
            *(short8*)&kbuf[nb][1][r0 + 64][sub * 8] = g3;
            cur = nb;
        }
    }

    // write partials; C layout (verified): col=lane&31, row=(r&3)+8*(r>>2)+4*kg
#pragma unroll
    for (int r = 0; r < 16; ++r) {
        const int q = q0 + qg * 32 + 4 * kg + (r & 3) + 8 * (r >> 2);
        const size_t t = (((size_t)q * D_ + d) << 7) + jrow;
        const size_t pp = (size_t)half * NT_ + t;
        m1p[pp] = m1[r]; m2p[pp] = m2[r]; b1p[pp] = b1[r];
    }
}

// ---------------------------------------------------------------------------
// Merge split-b partials -> final argmax index + near-tie flag list.
// ---------------------------------------------------------------------------
__global__ void k_merge(const float* __restrict__ m1p, const float* __restrict__ m2p,
                        const int* __restrict__ b1p, int* __restrict__ idx0,
                        int* __restrict__ flag_cnt, int* __restrict__ flag_list)
{
    int t = blockIdx.x * 256 + threadIdx.x;
    if (t >= NT_) return;
    float m1 = -3e38f, m2 = -3e38f;
    int i1 = 0;
#pragma unroll
    for (int h = 0; h < SPLIT_; ++h) {
        float a    = m1p[(size_t)h * NT_ + t];
        float bsec = m2p[(size_t)h * NT_ + t];
        int   ib   = b1p[(size_t)h * NT_ + t];
        if (a > m1) { m2 = m1; m1 = a; i1 = ib; }
        else if (a > m2) m2 = a;
        if (bsec > m2) m2 = bsec;
    }
    idx0[t] = i1;
    if (m2 >= m1 - MARGIN_) {
        int pos = atomicAdd(flag_cnt, 1);
        if (pos < NT_) flag_list[pos] = t;
    }
}

// ---------------------------------------------------------------------------
// K2: gather. Writes all 512 MB of output (hard-argmax rows).
// ---------------------------------------------------------------------------
__global__ void k_gather(const float* __restrict__ key_db, const float* __restrict__ value_db,
                         const int* __restrict__ idx0, float4* __restrict__ out)
{
    const int total = NT_ * 16 * 2;   // 33,554,432 float4
    for (int e = blockIdx.x * 256 + threadIdx.x; e < total; e += gridDim.x * 256) {
        int half = e >> 24;
        int rem  = e & 0xFFFFFF;
        int t  = rem >> 4;
        int fc = rem & 15;
        int j = t & 127;
        int d = (t >> 7) & 7;
        int b = idx0[t];
        const float* db = half ? value_db : key_db;
        int n = b * NB_ + j;
        out[e] = *reinterpret_cast<const float4*>(db + ((size_t)d * DB_ + n) * F_ + fc * 4);
    }
}

// ---------------------------------------------------------------------------
// K3: exact fp64 fix-up for flagged near-tie triples. One wave per triple.
// ---------------------------------------------------------------------------
__global__ void k_fix(const float* __restrict__ query, const float* __restrict__ key_db,
                      const float* __restrict__ value_db, const int* __restrict__ flag_cnt,
                      const int* __restrict__ flag_list, float* __restrict__ out)
{
    int cnt = *flag_cnt;
    if (cnt > NT_) cnt = NT_;
    int gw   = (blockIdx.x * blockDim.x + threadIdx.x) >> 6;
    int lane = threadIdx.x & 63;
    int nw   = (gridDim.x * blockDim.x) >> 6;

    for (int w = gw; w < cnt; w += nw) {
        int t = flag_list[w];
        int j = t & 127, d = (t >> 7) & 7, qi = t >> 10;
        const float* qrow = query + ((size_t)qi * D_ + d) * F_;
        const float* kb = key_db + (size_t)d * DB_ * F_;
        const float* vb = value_db + (size_t)d * DB_ * F_;

        double sv[4];
#pragma unroll
        for (int i = 0; i < 4; ++i) {
            int b = lane * 4 + i;
            const float* krow = kb + ((size_t)b * NB_ + j) * F_;
            double a = 0.0;
            for (int k2 = 0; k2 < F_; ++k2) a += (double)qrow[k2] * (double)krow[k2];
            sv[i] = a;
        }
        double m = fmax(fmax(sv[0], sv[1]), fmax(sv[2], sv[3]));
        for (int off = 32; off; off >>= 1) m = fmax(m, __shfl_xor(m, off));
        double ev[4];
        double es = 0.0;
#pragma unroll
        for (int i = 0; i < 4; ++i) { ev[i] = exp((sv[i] - m) * 1e6); es += ev[i]; }
        for (int off = 32; off; off >>= 1) es += __shfl_xor(es, off);
        double inv = 1.0 / es;
#pragma unroll
        for (int i = 0; i < 4; ++i) ev[i] *= inv;

        double ak = 0.0, av = 0.0;
        for (int src = 0; src < 64; ++src) {
#pragma unroll
            for (int i = 0; i < 4; ++i) {
                double wv = __shfl(ev[i], src);
                if (wv > 1e-300) {
                    int b = src * 4 + i;
                    size_t o = ((size_t)b * NB_ + j) * F_ + lane;
                    ak += wv * (double)kb[o];
                    av += wv * (double)vb[o];
                }
            }
        }
        out[(size_t)t * F_ + lane] = (float)ak;
        out[(size_t)NT_ * F_ + (size_t)t * F_ + lane] = (float)av;
    }
}

// ---------------------------------------------------------------------------
extern "C" void kernel_launch(void* const* d_in, const int* in_sizes, int n_in,
                              void* d_out, int out_size, void* d_ws, size_t ws_size,
                              hipStream_t stream)
{
    const float* query    = (const float*)d_in[0];
    const float* key_db   = (const float*)d_in[1];
    const float* value_db = (const float*)d_in[2];
    float* out = (float*)d_out;

    // ws layout (~8.4 MB): idx0[NT] | flag_cnt | flag_list[NT]
    int* idx0      = (int*)d_ws;
    int* flag_cnt  = (int*)((char*)d_ws + (size_t)NT_ * 4);
    int* flag_list = (int*)((char*)d_ws + (size_t)NT_ * 4 + 256);

    // Scratch parked in the not-yet-written front of d_out (~83 MB of 512 MB):
    // fp16 copies of keys+queries, then split-b partials. k_gather overwrites
    // every byte of d_out afterwards; all reads happen before.
    _Float16* k16 = (_Float16*)d_out;                    // 33.5 MB
    _Float16* q16 = k16 + (size_t)D_ * DB_ * F_;         // 1 MB
    float* m1p = (float*)(q16 + (size_t)Q_ * D_ * F_);   // 16 MB
    float* m2p = m1p + (size_t)SPLIT_ * NT_;             // 16 MB
    int*   b1p = (int*)(m2p + (size_t)SPLIT_ * NT_);     // 16 MB

    hipMemsetAsync(flag_cnt, 0, 4, stream);

    k_conv16   <<<2048, 256, 0, stream>>>(key_db, k16, D_ * DB_ * F_ / 8);
    k_convq16  <<<512,  256, 0, stream>>>(query, q16);
    k_scan_mfma<<<512,  512, 0, stream>>>(k16, q16, m1p, m2p, b1p);
    k_merge    <<<NT_ / 256, 256, 0, stream>>>(m1p, m2p, b1p, idx0, flag_cnt, flag_list);
    k_gather   <<<2048, 256, 0, stream>>>(key_db, value_db, idx0, (float4*)d_out);
    k_fix      <<<2048, 256, 0, stream>>>(query, key_db, value_db, flag_cnt, flag_list, out);
}

// Round 6
// 393.702 us; speedup vs baseline: 1.4585x; 1.4585x over previous
//
#include <hip/hip_runtime.h>

// Problem constants (fixed by the reference)
#define D_   8
#define Q_   1024
#define DB_  32768
#define F_   64
#define NB_  128      // num_buckets = num_neighbors
#define BS_  256      // bucket_size = DB/NB
#define NT_  (Q_*D_*NB_)   // 1,048,576 (q,d,j) triples
#define SPLIT_ 8      // split of the b-range across blocks
#define MARGIN_  5e-4f  // scan top-2 gap below which fixA re-ranks exactly
                        // (bf16 3-pass score err sigma ~3e-5 -> 16-sigma margin)
#define MARGIN2_ 2e-4   // fixA exact gap below which fixB does fp64 softmax
#define FLAG_CAP_ (NT_ - 4096)

typedef __attribute__((ext_vector_type(16))) float  f32x16;
typedef __attribute__((ext_vector_type(8)))  short  short8;
typedef __attribute__((ext_vector_type(4)))  short  short4v;
typedef __attribute__((ext_vector_type(8)))  __bf16 bf16x8;

static __device__ __forceinline__ short f2bf(float x) {   // RNE float->bf16
    unsigned u = __float_as_uint(x);
    u += 0x7fffu + ((u >> 16) & 1u);
    return (short)(u >> 16);
}
static __device__ __forceinline__ float bf2f(short h) {
    return __uint_as_float(((unsigned)(unsigned short)h) << 16);
}
static __device__ __forceinline__ f32x16 mfma32(short8 a, short8 b, f32x16 c) {
    return __builtin_amdgcn_mfma_f32_32x32x16_bf16(
        __builtin_bit_cast(bf16x8, a), __builtin_bit_cast(bf16x8, b), c, 0, 0, 0);
}

// ---------------------------------------------------------------------------
// Split-bf16 conversion: x = hi + lo, both bf16 (RNE). Keys: elementwise.
// ---------------------------------------------------------------------------
__global__ void k_conv(const float* __restrict__ src, short* __restrict__ hi,
                       short* __restrict__ lo, int n4)
{
    for (int i = blockIdx.x * 256 + threadIdx.x; i < n4; i += gridDim.x * 256) {
        float4 v = ((const float4*)src)[i];
        short4v h, l;
        h.x = f2bf(v.x); l.x = f2bf(v.x - bf2f(h.x));
        h.y = f2bf(v.y); l.y = f2bf(v.y - bf2f(h.y));
        h.z = f2bf(v.z); l.z = f2bf(v.z - bf2f(h.z));
        h.w = f2bf(v.w); l.w = f2bf(v.w - bf2f(h.w));
        *(short4v*)(hi + (size_t)i * 4) = h;
        *(short4v*)(lo + (size_t)i * 4) = l;
    }
}

// Query conversion with (Q,D,F) -> (D,Q,F) transpose.
__global__ void k_convq(const float* __restrict__ q, short* __restrict__ hi,
                        short* __restrict__ lo)
{
    int i = blockIdx.x * 256 + threadIdx.x;   // exactly Q_*D_*F_/4 threads
    int c = i & 15, d = (i >> 4) & 7, qq = i >> 7;
    float4 v = *(const float4*)(q + ((size_t)qq * D_ + d) * F_ + c * 4);
    short4v h, l;
    h.x = f2bf(v.x); l.x = f2bf(v.x - bf2f(h.x));
    h.y = f2bf(v.y); l.y = f2bf(v.y - bf2f(h.y));
    h.z = f2bf(v.z); l.z = f2bf(v.z - bf2f(h.z));
    h.w = f2bf(v.w); l.w = f2bf(v.w - bf2f(h.w));
    size_t o = ((size_t)d * Q_ + qq) * F_ + c * 4;
    *(short4v*)(hi + o) = h;
    *(short4v*)(lo + o) = l;
}

// ---------------------------------------------------------------------------
// K1: bf16 3-pass MFMA scan. Block = 64q x 128j (512 thr, 8 waves = 2qg x
// 4jg), each wave one 32x32 tile/step. One b-step per barrier phase (32
// phases), double-buffered 72KB LDS (hi+lo parts, rows padded +8 -> 144B
// stride, conflict-free b128). K-fragments read one-at-a-time interleaved
// with MFMA (register economy); all 3 passes accumulate into ONE C.
// L2 budget: d = XCD id, so each XCD streams only dataset d; concurrent
// slabs = 4 halves x 1MB = 4MB = L2, each shared by 16 co-resident blocks.
// ---------------------------------------------------------------------------
__global__ __launch_bounds__(512, 4) void k_scan_mfma(
    const short* __restrict__ khi, const short* __restrict__ klo,
    const short* __restrict__ qhi, const short* __restrict__ qlo,
    float* __restrict__ m1p, float* __restrict__ m2p, int* __restrict__ b1p)
{
    __shared__ short kbuf[2][2][128][72];   // [buf][part][row][col] = 72 KB
    const int tid  = threadIdx.x;
    const int d    = blockIdx.x & 7;        // dataset pinned to XCD
    const int idx  = blockIdx.x >> 3;       // 0..127 per XCD
    const int qi   = idx & 15;
    const int half = idx >> 4;              // 0..7
    const int q0 = qi * 64;
    const int wv = tid >> 6, lane = tid & 63;
    const int qg = wv >> 2, jg = wv & 3;
    const int lrow = lane & 31, kg = lane >> 5;

    // hoist Q fragments (A-operand): row = lane&31, 8 bf16 at f = ks*16+kg*8
    short8 qh[4], ql[4];
    {
        const size_t qoff = ((size_t)d * Q_ + q0 + qg * 32 + lrow) * F_ + kg * 8;
#pragma unroll
        for (int ks = 0; ks < 4; ++ks) {
            qh[ks] = *(const short8*)(qhi + qoff + ks * 16);
            ql[ks] = *(const short8*)(qlo + qoff + ks * 16);
        }
    }

    float m1[16], m2[16]; int b1[16];
#pragma unroll
    for (int r = 0; r < 16; ++r) { m1[r] = -3e38f; m2[r] = -3e38f; b1[r] = 0; }

    const int nsteps = BS_ / SPLIT_;       // 32 b-steps per block
    const int bstart = half * nsteps;
    // staging: thread t covers 16B chunks t and t+512 of each part per step
    const int r0 = tid >> 3, sub8 = (tid & 7) * 8;
    const short* sph = khi + (size_t)d * DB_ * F_ + (size_t)bstart * NB_ * F_
                     + (size_t)tid * 8;
    const short* spl = klo + (size_t)d * DB_ * F_ + (size_t)bstart * NB_ * F_
                     + (size_t)tid * 8;
    // per-step global stride = 128 rows * 64 F = 8192 shorts

    { // prologue: stage step 0 into buf 0
        short8 g0 = *(const short8*)(sph);
        short8 g1 = *(const short8*)(sph + 4096);
        short8 g2 = *(const short8*)(spl);
        short8 g3 = *(const short8*)(spl + 4096);
        *(short8*)&kbuf[0][0][r0     ][sub8] = g0;
        *(short8*)&kbuf[0][0][r0 + 64][sub8] = g1;
        *(short8*)&kbuf[0][1][r0     ][sub8] = g2;
        *(short8*)&kbuf[0][1][r0 + 64][sub8] = g3;
    }

    const int jrow = jg * 32 + lrow;       // j index 0..127
    int cur = 0;
    for (int p = 0; p < nsteps; ++p) {
        __syncthreads();                   // buf[cur] ready; buf[cur^1] free
        short8 g0, g1, g2, g3;
        if (p + 1 < nsteps) {              // issue next-step loads early
            const short* nh = sph + (size_t)(p + 1) * 8192;
            const short* nl = spl + (size_t)(p + 1) * 8192;
            g0 = *(const short8*)(nh);
            g1 = *(const short8*)(nh + 4096);
            g2 = *(const short8*)(nl);
            g3 = *(const short8*)(nl + 4096);
        }

        f32x16 c = {0,0,0,0,0,0,0,0,0,0,0,0,0,0,0,0};
#pragma unroll
        for (int ks = 0; ks < 4; ++ks) {   // hi-part fragment used twice
            short8 kf = *(const short8*)&kbuf[cur][0][jrow][ks * 16 + kg * 8];
            c = mfma32(qh[ks], kf, c);
            c = mfma32(ql[ks], kf, c);
        }
#pragma unroll
        for (int ks = 0; ks < 4; ++ks) {   // lo-part fragment used once
            short8 kf = *(const short8*)&kbuf[cur][1][jrow][ks * 16 + kg * 8];
            c = mfma32(qh[ks], kf, c);
        }

        const int b = bstart + p;
        // branchless top-2: med3 = new 2nd-max in one instruction
#pragma unroll
        for (int r = 0; r < 16; ++r) {
            float v = c[r];
            b1[r] = (v > m1[r]) ? b : b1[r];
            m2[r] = __builtin_amdgcn_fmed3f(v, m1[r], m2[r]);
            m1[r] = fmaxf(m1[r], v);
        }

        if (p + 1 < nsteps) {
            const int nb = cur ^ 1;
            *(short8*)&kbuf[nb][0][r0     ][sub8] = g0;
            *(short8*)&kbuf[nb][0][r0 + 64][sub8] = g1;
            *(short8*)&kbuf[nb][1][r0     ][sub8] = g2;
            *(short8*)&kbuf[nb][1][r0 + 64][sub8] = g3;
            cur = nb;
        }
    }

    // write partials; C layout (verified): col=lane&31, row=(r&3)+8*(r>>2)+4*kg
#pragma unroll
    for (int r = 0; r < 16; ++r) {
        const int q = q0 + qg * 32 + 4 * kg + (r & 3) + 8 * (r >> 2);
        const size_t t = (((size_t)q * D_ + d) << 7) + jrow;
        const size_t pp = (size_t)half * NT_ + t;
        m1p[pp] = m1[r]; m2p[pp] = m2[r]; b1p[pp] = b1[r];
    }
}

// ---------------------------------------------------------------------------
// Merge split-b partials -> final argmax index + near-tie flag list.
// ---------------------------------------------------------------------------
__global__ void k_merge(const float* __restrict__ m1p, const float* __restrict__ m2p,
                        const int* __restrict__ b1p, int* __restrict__ idx0,
                        int* __restrict__ flag_cnt, int* __restrict__ flag_list)
{
    int t = blockIdx.x * 256 + threadIdx.x;
    if (t >= NT_) return;
    float m1 = -3e38f, m2 = -3e38f;
    int i1 = 0;
#pragma unroll
    for (int h = 0; h < SPLIT_; ++h) {
        float a    = m1p[(size_t)h * NT_ + t];
        float bsec = m2p[(size_t)h * NT_ + t];
        int   ib   = b1p[(size_t)h * NT_ + t];
        if (a > m1) { m2 = m1; m1 = a; i1 = ib; }
        else if (a > m2) m2 = a;
        if (bsec > m2) m2 = bsec;
    }
    idx0[t] = i1;
    if (m2 >= m1 - MARGIN_) {
        int pos = atomicAdd(flag_cnt, 1);
        if (pos < FLAG_CAP_) flag_list[pos] = t;
    }
}

// ---------------------------------------------------------------------------
// FixA: exact fp64-accum re-rank of flagged triples (reads fp32 keys).
// One wave per triple. Patches idx0 BEFORE gather; escalates true near-ties
// (gap < MARGIN2_) to the fp64-softmax fixB list.
// ---------------------------------------------------------------------------
__global__ void k_fixA(const float* __restrict__ query, const float* __restrict__ key_db,
                       const int* __restrict__ flag_cnt, const int* __restrict__ flag_list,
                       int* __restrict__ idx0, int* __restrict__ flag2_cnt,
                       int* __restrict__ flag2_list)
{
    int cnt = *flag_cnt;
    if (cnt > FLAG_CAP_) cnt = FLAG_CAP_;
    int gw   = (blockIdx.x * blockDim.x + threadIdx.x) >> 6;
    int lane = threadIdx.x & 63;
    int nw   = (gridDim.x * blockDim.x) >> 6;

    for (int w = gw; w < cnt; w += nw) {
        int t = flag_list[w];
        int j = t & 127, d = (t >> 7) & 7, qi = t >> 10;
        const float* qrow = query + ((size_t)qi * D_ + d) * F_;
        const float* kb = key_db + (size_t)d * DB_ * F_;

        double m1 = -1e300, m2 = -1e300; int i1 = 0;
#pragma unroll
        for (int i = 0; i < 4; ++i) {
            int b = lane * 4 + i;
            const float* krow = kb + ((size_t)b * NB_ + j) * F_;
            double a = 0.0;
            for (int k2 = 0; k2 < F_; ++k2) a += (double)qrow[k2] * (double)krow[k2];
            if (a > m1) { m2 = m1; m1 = a; i1 = b; }
            else if (a > m2) m2 = a;
        }
        for (int off = 32; off; off >>= 1) {
            double om1 = __shfl_xor(m1, off);
            double om2 = __shfl_xor(m2, off);
            int    oi  = __shfl_xor(i1, off);
            if (om1 > m1) { m2 = fmax(m1, om2); m1 = om1; i1 = oi; }
            else { m2 = fmax(m2, fmax(om1, om2) == om1 ? om1 : om1); }
        }
        if (lane == 0) {
            idx0[t] = i1;
            if (m1 - m2 < MARGIN2_) {
                int pos = atomicAdd(flag2_cnt, 1);
                if (pos < 4096) flag2_list[pos] = t;
            }
        }
    }
}

// ---------------------------------------------------------------------------
// K2: gather. Writes all 512 MB of output (hard-argmax rows).
// ---------------------------------------------------------------------------
__global__ void k_gather(const float* __restrict__ key_db, const float* __restrict__ value_db,
                         const int* __restrict__ idx0, float4* __restrict__ out)
{
    const int total = NT_ * 16 * 2;   // 33,554,432 float4
    for (int e = blockIdx.x * 256 + threadIdx.x; e < total; e += gridDim.x * 256) {
        int half = e >> 24;
        int rem  = e & 0xFFFFFF;
        int t  = rem >> 4;
        int fc = rem & 15;
        int j = t & 127;
        int d = (t >> 7) & 7;
        int b = idx0[t];
        const float* db = half ? value_db : key_db;
        int n = b * NB_ + j;
        out[e] = *reinterpret_cast<const float4*>(db + ((size_t)d * DB_ + n) * F_ + fc * 4);
    }
}

// ---------------------------------------------------------------------------
// FixB: exact fp64 softmax for true near-tie triples. One wave per triple.
// ---------------------------------------------------------------------------
__global__ void k_fixB(const float* __restrict__ query, const float* __restrict__ key_db,
                       const float* __restrict__ value_db, const int* __restrict__ flag_cnt,
                       const int* __restrict__ flag_list, float* __restrict__ out)
{
    int cnt = *flag_cnt;
    if (cnt > 4096) cnt = 4096;
    int gw   = (blockIdx.x * blockDim.x + threadIdx.x) >> 6;
    int lane = threadIdx.x & 63;
    int nw   = (gridDim.x * blockDim.x) >> 6;

    for (int w = gw; w < cnt; w += nw) {
        int t = flag_list[w];
        int j = t & 127, d = (t >> 7) & 7, qi = t >> 10;
        const float* qrow = query + ((size_t)qi * D_ + d) * F_;
        const float* kb = key_db + (size_t)d * DB_ * F_;
        const float* vb = value_db + (size_t)d * DB_ * F_;

        double sv[4];
#pragma unroll
        for (int i = 0; i < 4; ++i) {
            int b = lane * 4 + i;
            const float* krow = kb + ((size_t)b * NB_ + j) * F_;
            double a = 0.0;
            for (int k2 = 0; k2 < F_; ++k2) a += (double)qrow[k2] * (double)krow[k2];
            sv[i] = a;
        }
        double m = fmax(fmax(sv[0], sv[1]), fmax(sv[2], sv[3]));
        for (int off = 32; off; off >>= 1) m = fmax(m, __shfl_xor(m, off));
        double ev[4];
        double es = 0.0;
#pragma unroll
        for (int i = 0; i < 4; ++i) { ev[i] = exp((sv[i] - m) * 1e6); es += ev[i]; }
        for (int off = 32; off; off >>= 1) es += __shfl_xor(es, off);
        double inv = 1.0 / es;
#pragma unroll
        for (int i = 0; i < 4; ++i) ev[i] *= inv;

        double ak = 0.0, av = 0.0;
        for (int src = 0; src < 64; ++src) {
#pragma unroll
            for (int i = 0; i < 4; ++i) {
                double wv = __shfl(ev[i], src);
                if (wv > 1e-300) {
                    int b = src * 4 + i;
                    size_t o = ((size_t)b * NB_ + j) * F_ + lane;
                    ak += wv * (double)kb[o];
                    av += wv * (double)vb[o];
                }
            }
        }
        out[(size_t)t * F_ + lane] = (float)ak;
        out[(size_t)NT_ * F_ + (size_t)t * F_ + lane] = (float)av;
    }
}

// ---------------------------------------------------------------------------
extern "C" void kernel_launch(void* const* d_in, const int* in_sizes, int n_in,
                              void* d_out, int out_size, void* d_ws, size_t ws_size,
                              hipStream_t stream)
{
    const float* query    = (const float*)d_in[0];
    const float* key_db   = (const float*)d_in[1];
    const float* value_db = (const float*)d_in[2];
    float* out = (float*)d_out;

    // ws layout (~8.4 MB): idx0[NT] | flag_cnt,flag2_cnt | flag_list | flag2_list
    int* idx0       = (int*)d_ws;
    int* flag_cnt   = (int*)((char*)d_ws + (size_t)NT_ * 4);
    int* flag2_cnt  = flag_cnt + 1;
    int* flag_list  = (int*)((char*)d_ws + (size_t)NT_ * 4 + 256);
    int* flag2_list = flag_list + FLAG_CAP_;

    // Scratch parked in the not-yet-written front of d_out (~165 MB of 512):
    // bf16 hi/lo copies of keys+queries, then split-b partials. k_gather
    // overwrites every byte of d_out afterwards; all reads happen before.
    short* khi = (short*)d_out;                          // 33.5 MB
    short* klo = khi + (size_t)D_ * DB_ * F_;            // 33.5 MB
    short* qhi = klo + (size_t)D_ * DB_ * F_;            // 1 MB
    short* qlo = qhi + (size_t)Q_ * D_ * F_;             // 1 MB
    float* m1p = (float*)(qlo + (size_t)Q_ * D_ * F_);   // 32 MB
    float* m2p = m1p + (size_t)SPLIT_ * NT_;             // 32 MB
    int*   b1p = (int*)(m2p + (size_t)SPLIT_ * NT_);     // 32 MB

    hipMemsetAsync(flag_cnt, 0, 8, stream);

    k_conv     <<<2048, 256, 0, stream>>>(key_db, khi, klo, D_ * DB_ * F_ / 4);
    k_convq    <<<512,  256, 0, stream>>>(query, qhi, qlo);
    k_scan_mfma<<<1024, 512, 0, stream>>>(khi, klo, qhi, qlo, m1p, m2p, b1p);
    k_merge    <<<NT_ / 256, 256, 0, stream>>>(m1p, m2p, b1p, idx0, flag_cnt, flag_list);
    k_fixA     <<<512,  256, 0, stream>>>(query, key_db, flag_cnt, flag_list,
                                          idx0, flag2_cnt, flag2_list);
    k_gather   <<<2048, 256, 0, stream>>>(key_db, value_db, idx0, (float4*)d_out);
    k_fixB     <<<256,  256, 0, stream>>>(query, key_db, value_db, flag2_cnt,
                                          flag2_list, out);
}

// Round 8
// 339.548 us; speedup vs baseline: 1.6911x; 1.1595x over previous
//
#include <hip/hip_runtime.h>

// Problem constants (fixed by the reference)
#define D_   8
#define Q_   1024
#define DB_  32768
#define F_   64
#define NB_  128      // num_buckets = num_neighbors
#define BS_  256      // bucket_size = DB/NB
#define NT_  (Q_*D_*NB_)   // 1,048,576 (q,d,j) triples
#define SPLIT_ 8      // split of the b-range across blocks
#define MARGIN_  5e-4f  // scan top-2 gap below which fixA re-ranks exactly
#define MARGIN2_ 2e-4   // fixA exact gap below which fixB does fp64 softmax
#define FLAG_CAP_ 262144

typedef __attribute__((ext_vector_type(16))) float    f32x16;
typedef __attribute__((ext_vector_type(4)))  float    f32x4;
typedef __attribute__((ext_vector_type(8)))  short    short8;
typedef __attribute__((ext_vector_type(4)))  unsigned uint4v;
typedef __attribute__((ext_vector_type(8)))  __bf16   bf16x8;

static __device__ __forceinline__ f32x16 mfma32(short8 a, short8 b, f32x16 c) {
    return __builtin_amdgcn_mfma_f32_32x32x16_bf16(
        __builtin_bit_cast(bf16x8, a), __builtin_bit_cast(bf16x8, b), c, 0, 0, 0);
}

// ---------------------------------------------------------------------------
// In-register split-bf16 conversion (bit-identical to R6's f2bf math).
// bfr: RNE-rounded bf16 kept in the TOP 16 bits (float-valued).
// cvt_pair packs two elements' bf16 into one dword via v_perm_b32.
// NOTE: the same helpers convert BOTH Q (A-operand) and K (B-operand), so
// even if the perm byte-source convention were flipped (pair swap), the
// identical within-pair k-permutation on A and B cancels in the dot product.
// ---------------------------------------------------------------------------
static __device__ __forceinline__ unsigned bfr(float x) {
    unsigned u = __float_as_uint(x);
    return (u + 0x7fffu + ((u >> 16) & 1u)) & 0xFFFF0000u;
}
static __device__ __forceinline__ unsigned cvt_hi(float x0, float x1) {
    return __builtin_amdgcn_perm(bfr(x1), bfr(x0), 0x07060302u);
}
static __device__ __forceinline__ unsigned cvt_lo(float x0, float x1) {
    unsigned a = bfr(x0), b = bfr(x1);
    unsigned la = bfr(x0 - __uint_as_float(a));
    unsigned lb = bfr(x1 - __uint_as_float(b));
    return __builtin_amdgcn_perm(lb, la, 0x07060302u);
}
static __device__ __forceinline__ void cvt8(float4 p, float4 q,
                                            uint4v& h, uint4v& l) {
    unsigned h0 = cvt_hi(p.x, p.y), l0 = cvt_lo(p.x, p.y);
    unsigned h1 = cvt_hi(p.z, p.w), l1 = cvt_lo(p.z, p.w);
    unsigned h2 = cvt_hi(q.x, q.y), l2 = cvt_lo(q.x, q.y);
    unsigned h3 = cvt_hi(q.z, q.w), l3 = cvt_lo(q.z, q.w);
    uint4v hh = { h0, h1, h2, h3 };
    uint4v ll = { l0, l1, l2, l3 };
    h = hh; l = ll;
}

// ---------------------------------------------------------------------------
// K1: bf16 3-pass MFMA scan with FUSED fp32->hi/lo conversion (no conv
// kernels, no bf16 key copies in memory: staged bytes = fp32 bytes).
// Block = 64q x 128j (512 thr, 8 waves = 2qg x 4jg), one 32x32 tile per
// wave per b-step. One b-step per barrier phase (32), double-buffered 72KB
// LDS (hi+lo parts, rows padded +8 -> conflict-free b128). All 3 passes
// accumulate into ONE C. d = XCD id: per-XCD concurrent fp32 slabs =
// 4 halves x 1MB = 4MB = L2, each shared by 16 co-resident qi-blocks.
// ---------------------------------------------------------------------------
__global__ __launch_bounds__(512, 4) void k_scan_mfma(
    const float* __restrict__ key_db, const float* __restrict__ query,
    float* __restrict__ m1p, float* __restrict__ m2p,
    unsigned char* __restrict__ b1p)
{
    __shared__ short kbuf[2][2][128][72];   // [buf][part][row][col] = 72 KB
    const int tid  = threadIdx.x;
    const int d    = blockIdx.x & 7;        // dataset pinned to XCD
    const int idx  = blockIdx.x >> 3;       // 0..127 per XCD
    const int qi   = idx & 15;
    const int half = idx >> 4;              // 0..7
    const int q0 = qi * 64;
    const int wv = tid >> 6, lane = tid & 63;
    const int qg = wv >> 2, jg = wv & 3;
    const int lrow = lane & 31, kg = lane >> 5;

    // Q fragments: convert fp32 -> hi/lo in-block (same pack path as keys)
    short8 qh[4], ql[4];
    {
        const float* qr = query + ((size_t)(q0 + qg * 32 + lrow) * D_ + d) * F_ + kg * 8;
#pragma unroll
        for (int ks = 0; ks < 4; ++ks) {
            float4 A = *(const float4*)(qr + ks * 16);
            float4 B = *(const float4*)(qr + ks * 16 + 4);
            uint4v h, l;
            cvt8(A, B, h, l);
            qh[ks] = __builtin_bit_cast(short8, h);
            ql[ks] = __builtin_bit_cast(short8, l);
        }
    }

    float m1[16], m2[16]; int b1[16];
#pragma unroll
    for (int r = 0; r < 16; ++r) { m1[r] = -3e38f; m2[r] = -3e38f; b1[r] = 0; }

    const int nsteps = BS_ / SPLIT_;       // 32 b-steps per block
    const int bstart = half * nsteps;
    // staging: thread covers rows r0 and r0+64, 8 cols at sub8
    const int r0 = tid >> 3, sub8 = (tid & 7) * 8;
    const float* sp = key_db + (size_t)d * DB_ * F_ + (size_t)bstart * NB_ * F_
                    + (size_t)r0 * F_ + sub8;
    // per-step global stride = 128 rows * 64 F floats

    { // prologue: stage step 0 into buf 0
        float4 A0 = *(const float4*)(sp);
        float4 A1 = *(const float4*)(sp + 4);
        float4 B0 = *(const float4*)(sp + 4096);
        float4 B1 = *(const float4*)(sp + 4096 + 4);
        uint4v h0, l0, h1, l1;
        cvt8(A0, A1, h0, l0);
        cvt8(B0, B1, h1, l1);
        *(short8*)&kbuf[0][0][r0     ][sub8] = __builtin_bit_cast(short8, h0);
        *(short8*)&kbuf[0][0][r0 + 64][sub8] = __builtin_bit_cast(short8, h1);
        *(short8*)&kbuf[0][1][r0     ][sub8] = __builtin_bit_cast(short8, l0);
        *(short8*)&kbuf[0][1][r0 + 64][sub8] = __builtin_bit_cast(short8, l1);
    }

    const int jrow = jg * 32 + lrow;       // j index 0..127
    int cur = 0;
    for (int p = 0; p < nsteps; ++p) {
        __syncthreads();                   // buf[cur] ready; buf[cur^1] free
        float4 A0, A1, B0, B1;
        if (p + 1 < nsteps) {              // issue next-step fp32 loads early
            const float* np = sp + (size_t)(p + 1) * (NB_ * F_);
            A0 = *(const float4*)(np);
            A1 = *(const float4*)(np + 4);
            B0 = *(const float4*)(np + 4096);
            B1 = *(const float4*)(np + 4096 + 4);
        }

        f32x16 c = {0,0,0,0,0,0,0,0,0,0,0,0,0,0,0,0};
#pragma unroll
        for (int ks = 0; ks < 4; ++ks) {   // hi-part fragment used twice
            short8 kf = *(const short8*)&kbuf[cur][0][jrow][ks * 16 + kg * 8];
            c = mfma32(qh[ks], kf, c);
            c = mfma32(ql[ks], kf, c);
        }
#pragma unroll
        for (int ks = 0; ks < 4; ++ks) {   // lo-part fragment used once
            short8 kf = *(const short8*)&kbuf[cur][1][jrow][ks * 16 + kg * 8];
            c = mfma32(qh[ks], kf, c);
        }

        const int b = bstart + p;
#pragma unroll
        for (int r = 0; r < 16; ++r) {     // branchless top-2 (med3/max)
            float v = c[r];
            b1[r] = (v > m1[r]) ? b : b1[r];
            m2[r] = __builtin_amdgcn_fmed3f(v, m1[r], m2[r]);
            m1[r] = fmaxf(m1[r], v);
        }

        if (p + 1 < nsteps) {              // convert + write next step late
            uint4v h0, l0, h1, l1;
            cvt8(A0, A1, h0, l0);
            cvt8(B0, B1, h1, l1);
            const int nb = cur ^ 1;
            *(short8*)&kbuf[nb][0][r0     ][sub8] = __builtin_bit_cast(short8, h0);
            *(short8*)&kbuf[nb][0][r0 + 64][sub8] = __builtin_bit_cast(short8, h1);
            *(short8*)&kbuf[nb][1][r0     ][sub8] = __builtin_bit_cast(short8, l0);
            *(short8*)&kbuf[nb][1][r0 + 64][sub8] = __builtin_bit_cast(short8, l1);
            cur = nb;
        }
    }

    // write partials; C layout (verified): col=lane&31, row=(r&3)+8*(r>>2)+4*kg
#pragma unroll
    for (int r = 0; r < 16; ++r) {
        const int q = q0 + qg * 32 + 4 * kg + (r & 3) + 8 * (r >> 2);
        const size_t t = (((size_t)q * D_ + d) << 7) + jrow;
        const size_t pp = (size_t)half * NT_ + t;
        m1p[pp] = m1[r]; m2p[pp] = m2[r]; b1p[pp] = (unsigned char)b1[r];
    }
}

// ---------------------------------------------------------------------------
// Merge split-b partials -> final argmax byte + near-tie flag list.
// ---------------------------------------------------------------------------
__global__ void k_merge(const float* __restrict__ m1p, const float* __restrict__ m2p,
                        const unsigned char* __restrict__ b1p,
                        unsigned char* __restrict__ idx0b,
                        int* __restrict__ flag_cnt, int* __restrict__ flag_list)
{
    int t = blockIdx.x * 256 + threadIdx.x;
    if (t >= NT_) return;
    float m1 = -3e38f, m2 = -3e38f;
    int i1 = 0;
#pragma unroll
    for (int h = 0; h < SPLIT_; ++h) {
        float a    = m1p[(size_t)h * NT_ + t];
        float bsec = m2p[(size_t)h * NT_ + t];
        int   ib   = b1p[(size_t)h * NT_ + t];
        if (a > m1) { m2 = m1; m1 = a; i1 = ib; }
        else if (a > m2) m2 = a;
        if (bsec > m2) m2 = bsec;
    }
    idx0b[t] = (unsigned char)i1;
    if (m2 >= m1 - MARGIN_) {
        int pos = atomicAdd(flag_cnt, 1);
        if (pos < FLAG_CAP_) flag_list[pos] = t;
    }
}

// ---------------------------------------------------------------------------
// FixA: exact fp64-accum re-rank of flagged triples (reads fp32 keys).
// One wave per triple; patches idx0b BEFORE gather; escalates true
// near-ties (gap < MARGIN2_) to the fp64-softmax fixB list.
// ---------------------------------------------------------------------------
__global__ void k_fixA(const float* __restrict__ query, const float* __restrict__ key_db,
                       const int* __restrict__ flag_cnt, const int* __restrict__ flag_list,
                       unsigned char* __restrict__ idx0b, int* __restrict__ flag2_cnt,
                       int* __restrict__ flag2_list)
{
    int cnt = *flag_cnt;
    if (cnt > FLAG_CAP_) cnt = FLAG_CAP_;
    int gw   = (blockIdx.x * blockDim.x + threadIdx.x) >> 6;
    int lane = threadIdx.x & 63;
    int nw   = (gridDim.x * blockDim.x) >> 6;

    for (int w = gw; w < cnt; w += nw) {
        int t = flag_list[w];
        int j = t & 127, d = (t >> 7) & 7, qi = t >> 10;
        const float* qrow = query + ((size_t)qi * D_ + d) * F_;
        const float* kb = key_db + (size_t)d * DB_ * F_;

        double m1 = -1e300, m2 = -1e300; int i1 = 0;
#pragma unroll
        for (int i = 0; i < 4; ++i) {
            int b = lane * 4 + i;
            const float* krow = kb + ((size_t)b * NB_ + j) * F_;
            double a = 0.0;
            for (int k2 = 0; k2 < F_; ++k2) a += (double)qrow[k2] * (double)krow[k2];
            if (a > m1) { m2 = m1; m1 = a; i1 = b; }
            else if (a > m2) m2 = a;
        }
        for (int off = 32; off; off >>= 1) {
            double om1 = __shfl_xor(m1, off);
            double om2 = __shfl_xor(m2, off);
            int    oi  = __shfl_xor(i1, off);
            if (om1 > m1) { m2 = fmax(m1, om2); m1 = om1; i1 = oi; }
            else          { m2 = fmax(m2, om1); }
        }
        if (lane == 0) {
            idx0b[t] = (unsigned char)i1;
            if (m1 - m2 < MARGIN2_) {
                int pos = atomicAdd(flag2_cnt, 1);
                if (pos < 4096) flag2_list[pos] = t;
            }
        }
    }
}

// ---------------------------------------------------------------------------
// K2: gather. Writes all 512 MB of output (hard-argmax rows).
// Non-temporal stores: keep the ~134MB row footprint resident in L2/L3.
// ---------------------------------------------------------------------------
__global__ void k_gather(const float* __restrict__ key_db, const float* __restrict__ value_db,
                         const unsigned char* __restrict__ idx0b, f32x4* __restrict__ out)
{
    const int total = NT_ * 16 * 2;   // 33,554,432 float4
    for (int e = blockIdx.x * 256 + threadIdx.x; e < total; e += gridDim.x * 256) {
        int half = e >> 24;
        int rem  = e & 0xFFFFFF;
        int t  = rem >> 4;
        int fc = rem & 15;
        int j = t & 127;
        int d = (t >> 7) & 7;
        int b = idx0b[t];
        const float* db = half ? value_db : key_db;
        int n = b * NB_ + j;
        f32x4 v = *reinterpret_cast<const f32x4*>(db + ((size_t)d * DB_ + n) * F_ + fc * 4);
        __builtin_nontemporal_store(v, &out[e]);
    }
}

// ---------------------------------------------------------------------------
// FixB: exact fp64 softmax for true near-tie triples. One wave per triple.
// ---------------------------------------------------------------------------
__global__ void k_fixB(const float* __restrict__ query, const float* __restrict__ key_db,
                       const float* __restrict__ value_db, const int* __restrict__ flag_cnt,
                       const int* __restrict__ flag_list, float* __restrict__ out)
{
    int cnt = *flag_cnt;
    if (cnt > 4096) cnt = 4096;
    int gw   = (blockIdx.x * blockDim.x + threadIdx.x) >> 6;
    int lane = threadIdx.x & 63;
    int nw   = (gridDim.x * blockDim.x) >> 6;

    for (int w = gw; w < cnt; w += nw) {
        int t = flag_list[w];
        int j = t & 127, d = (t >> 7) & 7, qi = t >> 10;
        const float* qrow = query + ((size_t)qi * D_ + d) * F_;
        const float* kb = key_db + (size_t)d * DB_ * F_;
        const float* vb = value_db + (size_t)d * DB_ * F_;

        double sv[4];
#pragma unroll
        for (int i = 0; i < 4; ++i) {
            int b = lane * 4 + i;
            const float* krow = kb + ((size_t)b * NB_ + j) * F_;
            double a = 0.0;
            for (int k2 = 0; k2 < F_; ++k2) a += (double)qrow[k2] * (double)krow[k2];
            sv[i] = a;
        }
        double m = fmax(fmax(sv[0], sv[1]), fmax(sv[2], sv[3]));
        for (int off = 32; off; off >>= 1) m = fmax(m, __shfl_xor(m, off));
        double ev[4];
        double es = 0.0;
#pragma unroll
        for (int i = 0; i < 4; ++i) { ev[i] = exp((sv[i] - m) * 1e6); es += ev[i]; }
        for (int off = 32; off; off >>= 1) es += __shfl_xor(es, off);
        double inv = 1.0 / es;
#pragma unroll
        for (int i = 0; i < 4; ++i) ev[i] *= inv;

        double ak = 0.0, av = 0.0;
        for (int src = 0; src < 64; ++src) {
#pragma unroll
            for (int i = 0; i < 4; ++i) {
                double wv = __shfl(ev[i], src);
                if (wv > 1e-300) {
                    int b = src * 4 + i;
                    size_t o = ((size_t)b * NB_ + j) * F_ + lane;
                    ak += wv * (double)kb[o];
                    av += wv * (double)vb[o];
                }
            }
        }
        out[(size_t)t * F_ + lane] = (float)ak;
        out[(size_t)NT_ * F_ + (size_t)t * F_ + lane] = (float)av;
    }
}

// ---------------------------------------------------------------------------
extern "C" void kernel_launch(void* const* d_in, const int* in_sizes, int n_in,
                              void* d_out, int out_size, void* d_ws, size_t ws_size,
                              hipStream_t stream)
{
    const float* query    = (const float*)d_in[0];
    const float* key_db   = (const float*)d_in[1];
    const float* value_db = (const float*)d_in[2];
    float* out = (float*)d_out;

    // ws layout (~2.1 MB): idx0b[NT bytes] | flag_cnt,flag2_cnt | flag_list | flag2_list
    unsigned char* idx0b = (unsigned char*)d_ws;
    int* flag_cnt   = (int*)((char*)d_ws + (size_t)NT_);
    int* flag2_cnt  = flag_cnt + 1;
    int* flag_list  = (int*)((char*)d_ws + (size_t)NT_ + 256);
    int* flag2_list = flag_list + FLAG_CAP_;

    // Scratch parked in the not-yet-written front of d_out (72 MB of 512):
    // split-b partials only (no key copies needed anymore). k_gather
    // overwrites every byte of d_out afterwards; all reads happen before.
    float* m1p = (float*)d_out;                           // 32 MB
    float* m2p = m1p + (size_t)SPLIT_ * NT_;              // 32 MB
    unsigned char* b1p = (unsigned char*)(m2p + (size_t)SPLIT_ * NT_); // 8 MB

    (void)hipMemsetAsync(flag_cnt, 0, 8, stream);

    k_scan_mfma<<<1024, 512, 0, stream>>>(key_db, query, m1p, m2p, b1p);
    k_merge    <<<NT_ / 256, 256, 0, stream>>>(m1p, m2p, b1p, idx0b, flag_cnt, flag_list);
    k_fixA     <<<512,  256, 0, stream>>>(query, key_db, flag_cnt, flag_list,
                                          idx0b, flag2_cnt, flag2_list);
    k_gather   <<<2048, 256, 0, stream>>>(key_db, value_db, idx0b, (f32x4*)d_out);
    k_fixB     <<<256,  256, 0, stream>>>(query, key_db, value_db, flag2_cnt,
                                          flag2_list, out);
}